// Round 9
// baseline (120.312 us; speedup 1.0000x reference)
//
#include <hip/hip_runtime.h>

constexpr int kB = 4, kC = 64, kH = 64, kW = 64, kN = kH * kW;
constexpr float kEps = 1e-5f;
// sqrt(log2(e)): folded into fbfA (used for BOTH Q and K) so S = QK^T lands in
// the log2 domain and exp becomes a bare v_exp_f32.
constexpr float kQS = 1.2011224087864498f;

#if __has_builtin(__builtin_amdgcn_exp2f)
#define EXP2F(x) __builtin_amdgcn_exp2f(x)
#else
#define EXP2F(x) exp2f(x)
#endif

typedef __attribute__((ext_vector_type(8))) short short8;
typedef __attribute__((ext_vector_type(4))) float f32x4;
typedef unsigned short u16;

__device__ inline unsigned pkbf(float a, float b) {  // RNE pack (pack path only)
  unsigned ua = __float_as_uint(a), ub = __float_as_uint(b);
  ua += 0x7fff + ((ua >> 16) & 1);
  ub += 0x7fff + ((ub >> 16) & 1);
  return (ua >> 16) | (ub & 0xffff0000u);
}

// ---- w[oc][ic][3][3] fp32 -> wA bf16 [oc][khw*64 + ic]; also zero stat shards
__global__ __launch_bounds__(256) void prep_w_kernel(const float* __restrict__ w,
                                                     u16* __restrict__ wA,
                                                     float* __restrict__ stat) {
  if (blockIdx.x == 0) {  // 4 shards x (64 sum + 64 sumsq)
    stat[threadIdx.x] = 0.f;
    stat[256 + threadIdx.x] = 0.f;
  }
  int idx = blockIdx.x * 256 + threadIdx.x;
  if (idx < 64 * 576) {
    int oc = idx / 576, r = idx - oc * 576;
    int khw = r >> 6, ic = r & 63;
    float v = w[(oc * 64 + ic) * 9 + khw];
    unsigned u = __float_as_uint(v);
    u += 0x7fff + ((u >> 16) & 1);
    wA[idx] = (u16)(u >> 16);
  }
}

// ---- conv 3x3 SAME + bias, bf16 MFMA implicit GEMM. block=(b,h,whalf), 4 waves.
//      Fused: per-channel sum/sumsq via in-wave shuffle reduce + sharded atomics.
__global__ __launch_bounds__(256) void conv_kernel(const float* __restrict__ x,
                                                   const u16* __restrict__ wA,
                                                   const float* __restrict__ bias,
                                                   float* __restrict__ y,
                                                   float* __restrict__ stat) {
  const int tid = threadIdx.x;
  const int lane = tid & 63;
  const int wv = tid >> 6;
  const int bx = blockIdx.x;
  const int b = bx >> 7;
  const int h = (bx & 127) >> 1;
  const int w0 = (bx & 1) * 32;
  const int lw = lane & 15, lg = lane >> 4;

  // xt[kh][wc 0..39][ic], wc <-> w = w0-4+wc ; ic-chunk8 swizzled by wc&7
  __shared__ __align__(16) u16 xt[3 * 40 * 64];

#pragma unroll
  for (int rep = 0; rep < 4; ++rep) {
    int idx = rep * 256 + tid;
    if (idx < 960) {
      int kh = idx / 320;
      int t = idx - kh * 320;
      int gw = t >> 5, icp = t & 31;
      int wb = w0 - 4 + gw * 4;
      int hh = h + kh - 1;
      float4 va = {0.f, 0.f, 0.f, 0.f}, vb = {0.f, 0.f, 0.f, 0.f};
      if (hh >= 0 && hh < 64 && wb >= 0 && wb < 64) {
        va = *(const float4*)&x[((b * 64 + icp * 2) * 64 + hh) * 64 + wb];
        vb = *(const float4*)&x[((b * 64 + icp * 2 + 1) * 64 + hh) * 64 + wb];
      }
      float av[4] = {va.x, va.y, va.z, va.w};
      float bv[4] = {vb.x, vb.y, vb.z, vb.w};
#pragma unroll
      for (int j = 0; j < 4; ++j) {
        int wc = gw * 4 + j;
        *(unsigned*)&xt[(kh * 40 + wc) * 64 + (((icp >> 2) ^ (wc & 7)) * 8 + (icp & 3) * 2)] =
            pkbf(av[j], bv[j]);
      }
    }
  }
  __syncthreads();

  const int oc0 = wv * 16;
  short8 af[18];
#pragma unroll
  for (int kc = 0; kc < 18; ++kc)
    af[kc] = *(const short8*)&wA[(oc0 + lw) * 576 + kc * 32 + lg * 8];

  f32x4 acc[2];
  acc[0] = (f32x4){0.f, 0.f, 0.f, 0.f};
  acc[1] = (f32x4){0.f, 0.f, 0.f, 0.f};
#pragma unroll
  for (int kc = 0; kc < 18; ++kc) {
    const int khw = kc >> 1;
    const int kh = khw / 3, kwv = khw % 3;
#pragma unroll
    for (int nt = 0; nt < 2; ++nt) {
      int wc = nt * 16 + lw + kwv + 3;
      short8 bf = *(const short8*)&xt[(kh * 40 + wc) * 64 + ((((kc & 1) * 4 + lg) ^ (wc & 7)) * 8)];
      acc[nt] = __builtin_amdgcn_mfma_f32_16x16x32_bf16(af[kc], bf, acc[nt], 0, 0, 0);
    }
  }

  float* st = stat + (bx & 3) * 128;  // 4 shards cut per-address atomic depth
#pragma unroll
  for (int r = 0; r < 4; ++r) {
    const int oc = oc0 + lg * 4 + r;
    const float bz = bias[oc];
    float v0 = acc[0][r] + bz;
    float v1 = acc[1][r] + bz;
    y[((b * 64 + oc) * 64 + h) * 64 + w0 + lw] = v0;
    y[((b * 64 + oc) * 64 + h) * 64 + w0 + 16 + lw] = v1;
    float s = v0 + v1, q = v0 * v0 + v1 * v1;
#pragma unroll
    for (int m = 1; m < 16; m <<= 1) {
      s += __shfl_xor(s, m);
      q += __shfl_xor(q, m);
    }
    if (lw == 0) {
      atomicAdd(&st[oc], s);
      atomicAdd(&st[64 + oc], q);
    }
  }
}

// ---- BN + PReLU -> fbfA (frag layout: pos=lane&15, ch=k, scaled by kQS);
//      fbfB (frag layout: ch=lane&15, pos=k). Computes A/B from fused stats,
//      publishes ABg for the attn epilogue.
__global__ __launch_bounds__(256) void pack_kernel(const float* __restrict__ y,
                                                   const float* __restrict__ stat,
                                                   const float* __restrict__ scale,
                                                   const float* __restrict__ bias,
                                                   const float* __restrict__ pa,
                                                   float* __restrict__ ABg,
                                                   u16* __restrict__ fbfA,
                                                   u16* __restrict__ fbfB) {
  __shared__ float ls[64 * 65];
  __shared__ float sAB[128];
  const int tid = threadIdx.x;
  const int b = blockIdx.x >> 6;
  const int n0 = (blockIdx.x & 63) << 6;
  if (tid < 64) {
    const float inv_n = 1.f / (float)(kB * kN);
    float ssum = stat[tid] + stat[128 + tid] + stat[256 + tid] + stat[384 + tid];
    float qsum = stat[64 + tid] + stat[192 + tid] + stat[320 + tid] + stat[448 + tid];
    float mean = ssum * inv_n;
    float var = qsum * inv_n - mean * mean;
    float A = scale[tid] * rsqrtf(var + kEps);
    float Bc = bias[tid] - mean * A;
    sAB[tid] = A;
    sAB[64 + tid] = Bc;
    ABg[tid] = A;       // redundant identical writes across blocks: benign
    ABg[64 + tid] = Bc;
  }
  __syncthreads();
  {
    const int c = tid >> 2, nj = (tid & 3) << 4;
    const float A = sAB[c], Bc = sAB[64 + c], a = pa[0];
    const float* yp = y + ((b * kC + c) * kN) + n0 + nj;
    float f[16];
#pragma unroll
    for (int v = 0; v < 4; ++v) {
      float4 xv = *(const float4*)(yp + v * 4);
      float t;
      t = fmaf(A, xv.x, Bc); f[v * 4 + 0] = t >= 0.f ? t : a * t;
      t = fmaf(A, xv.y, Bc); f[v * 4 + 1] = t >= 0.f ? t : a * t;
      t = fmaf(A, xv.z, Bc); f[v * 4 + 2] = t >= 0.f ? t : a * t;
      t = fmaf(A, xv.w, Bc); f[v * 4 + 3] = t >= 0.f ? t : a * t;
    }
#pragma unroll
    for (int v = 0; v < 16; ++v) ls[c * 65 + nj + v] = f[v];
  }
  __syncthreads();
  {  // fbfA: chunk = (pt within block 0..3, kc 0..1); 64 lanes x 16B per chunk
    int chunk = tid >> 5, pt = chunk >> 1, kc = chunk & 1;
    int lp2 = (tid & 31) * 2;
    u16* dst = fbfA + ((size_t)((b * 256 + (n0 >> 4) + pt) * 2 + kc)) * 512;
#pragma unroll
    for (int e = 0; e < 2; ++e) {
      int L = lp2 + e;
      int n = pt * 16 + (L & 15);
      int cb = kc * 32 + (L >> 4) * 8;
      float v[8];
#pragma unroll
      for (int r = 0; r < 8; ++r) v[r] = kQS * ls[(cb + r) * 65 + n];
      uint4 o = {pkbf(v[0], v[1]), pkbf(v[2], v[3]), pkbf(v[4], v[5]), pkbf(v[6], v[7])};
      *(uint4*)&dst[L * 8] = o;
    }
  }
  {  // fbfB: chunk = (jt 0..1, ct 0..3)
    int chunk = tid >> 5, jt = chunk >> 2, ct = chunk & 3;
    int lp2 = (tid & 31) * 2;
    u16* dst = fbfB + ((size_t)((b * 128 + (n0 >> 5) + jt) * 4 + ct)) * 512;
#pragma unroll
    for (int e = 0; e < 2; ++e) {
      int L = lp2 + e;
      int c = ct * 16 + (L & 15);
      int nb = jt * 32 + (L >> 4) * 8;
      float v[8];
#pragma unroll
      for (int r = 0; r < 8; ++r) v[r] = ls[c * 65 + nb + r];
      uint4 o = {pkbf(v[0], v[1]), pkbf(v[2], v[3]), pkbf(v[4], v[5]), pkbf(v[6], v[7])};
      *(uint4*)&dst[L * 8] = o;
    }
  }
}

// ---- FULL-j flash attention, fused epilogue, 4 waves/SIMD.
//      grid = 512 blocks (b x i32-half-tile-group) x 8 waves = 16 waves/CU.
//      Each wave computes the SAME 2 Q-tiles (32 i-rows) over 1/8 of all 128
//      j-tiles; 3-stage LDS tree reduction -> block-local normalization.
//      VGPR ~halves vs 4-tile version -> 4 waves/SIMD naturally (no cap).
//      XCD swizzle (512 % 8 == 0): each XCD's blocks span one half-batch ->
//      its 4MB fbfA/fbfB working set fits the per-XCD L2.
//      y/out intentionally not __restrict__ (they alias; same-thread RMW).
__global__ __launch_bounds__(512, 2) void attn_kernel(const u16* __restrict__ fbfA,
                                                      const u16* __restrict__ fbfB,
                                                      const float* y,
                                                      const float* __restrict__ ABg,
                                                      const float* __restrict__ pa,
                                                      const float* __restrict__ gamma_p,
                                                      float* out) {
  const int tid = threadIdx.x;
  const int lane = tid & 63;
  const int w = tid >> 6;
  const int bxr = blockIdx.x;
  const int bx = (bxr & 7) * 64 + (bxr >> 3);  // bijective XCD swizzle (512%8==0)
  const int b = bx >> 7, i32 = bx & 127;
  const int c15 = lane & 15, g = lane >> 4;

  // 40 KB union: [0,20480) per-wave P staging during the loop;
  // 4 x 10240B regions for tree reduction; region 1 reused as tr (8448 B).
  __shared__ __align__(16) float Red[10240];
  u16* ps = (u16*)Red + w * 1280;
  const int pw_off = c15 * 40 + g * 4;   // write base (elements)
  const int pr_off = c15 * 40 + g * 8;   // b128 read base

  const uint4* fA = (const uint4*)fbfA;
  const uint4* fB = (const uint4*)fbfB;

  // Q frags (negated; fbfA pre-scaled by sqrt(log2e) so S is log2-domain)
  uint4 qf[2][2];
#pragma unroll
  for (int it = 0; it < 2; ++it)
#pragma unroll
    for (int kc = 0; kc < 2; ++kc) {
      uint4 q = fA[(size_t)((b * 256 + i32 * 2 + it) * 2 + kc) * 64 + lane];
      q.x ^= 0x80008000u; q.y ^= 0x80008000u; q.z ^= 0x80008000u; q.w ^= 0x80008000u;
      qf[it][kc] = q;
    }

  const short8 ones = {0x3F80, 0x3F80, 0x3F80, 0x3F80, 0x3F80, 0x3F80, 0x3F80, 0x3F80};

  f32x4 oacc[2][4];
  f32x4 lacc[2];
#pragma unroll
  for (int it = 0; it < 2; ++it) {
    lacc[it] = (f32x4){0.f, 0.f, 0.f, 0.f};
#pragma unroll
    for (int ct = 0; ct < 4; ++ct) oacc[it][ct] = (f32x4){0.f, 0.f, 0.f, 0.f};
  }

#pragma unroll 2
  for (int jj2 = 0; jj2 < 16; ++jj2) {
    const int jj = jj2 * 8 + w;  // interleaved: 8 waves cover all 128 j-tiles
    // fragment loads (coalesced 1KB each, L2-resident per-XCD)
    const int ca = (b * 256 + jj * 2) * 2;
    uint4 a00 = fA[(size_t)(ca + 0) * 64 + lane];
    uint4 a01 = fA[(size_t)(ca + 1) * 64 + lane];
    uint4 a10 = fA[(size_t)(ca + 2) * 64 + lane];
    uint4 a11 = fA[(size_t)(ca + 3) * 64 + lane];
    const int cb = (b * 128 + jj) * 4;
    uint4 v0 = fB[(size_t)(cb + 0) * 64 + lane];
    uint4 v1 = fB[(size_t)(cb + 1) * 64 + lane];
    uint4 v2 = fB[(size_t)(cb + 2) * 64 + lane];
    uint4 v3 = fB[(size_t)(cb + 3) * 64 + lane];

    // S^T tiles (log2 domain): D[m=j][n=i]
    f32x4 sv[2][2];
#pragma unroll
    for (int it = 0; it < 2; ++it) {
      f32x4 z0 = (f32x4){0.f, 0.f, 0.f, 0.f};
      z0 = __builtin_amdgcn_mfma_f32_16x16x32_bf16(*(short8*)&a00, *(short8*)&qf[it][0], z0, 0, 0, 0);
      z0 = __builtin_amdgcn_mfma_f32_16x16x32_bf16(*(short8*)&a01, *(short8*)&qf[it][1], z0, 0, 0, 0);
      sv[0][it] = z0;
      f32x4 z1 = (f32x4){0.f, 0.f, 0.f, 0.f};
      z1 = __builtin_amdgcn_mfma_f32_16x16x32_bf16(*(short8*)&a10, *(short8*)&qf[it][0], z1, 0, 0, 0);
      z1 = __builtin_amdgcn_mfma_f32_16x16x32_bf16(*(short8*)&a11, *(short8*)&qf[it][1], z1, 0, 0, 0);
      sv[1][it] = z1;
    }
    // P = exp2(S) packed to per-wave LDS [i][j] (v_perm RTZ bf16 pack)
#pragma unroll
    for (int it = 0; it < 2; ++it)
#pragma unroll
      for (int jt = 0; jt < 2; ++jt) {
        float p0 = EXP2F(sv[jt][it][0]);
        float p1 = EXP2F(sv[jt][it][1]);
        float p2 = EXP2F(sv[jt][it][2]);
        float p3 = EXP2F(sv[jt][it][3]);
        uint2 d;
        d.x = __builtin_amdgcn_perm(__float_as_uint(p1), __float_as_uint(p0), 0x07060302u);
        d.y = __builtin_amdgcn_perm(__float_as_uint(p3), __float_as_uint(p2), 0x07060302u);
        *(uint2*)&ps[pw_off + it * 640 + jt * 16] = d;
      }
    // PV + l (ones-frag row sums)
#pragma unroll
    for (int it = 0; it < 2; ++it) {
      short8 pf = *(const short8*)&ps[pr_off + it * 640];
      lacc[it] = __builtin_amdgcn_mfma_f32_16x16x32_bf16(pf, ones, lacc[it], 0, 0, 0);
      oacc[it][0] = __builtin_amdgcn_mfma_f32_16x16x32_bf16(pf, *(short8*)&v0, oacc[it][0], 0, 0, 0);
      oacc[it][1] = __builtin_amdgcn_mfma_f32_16x16x32_bf16(pf, *(short8*)&v1, oacc[it][1], 0, 0, 0);
      oacc[it][2] = __builtin_amdgcn_mfma_f32_16x16x32_bf16(pf, *(short8*)&v2, oacc[it][2], 0, 0, 0);
      oacc[it][3] = __builtin_amdgcn_mfma_f32_16x16x32_bf16(pf, *(short8*)&v3, oacc[it][3], 0, 0, 0);
    }
  }

  // ---- 3-stage tree reduction: 8 -> 4 -> 2 -> 1 waves (uniform barriers).
  //      Payload/wave: 8 oacc + 2 lacc f32x4 per lane = 10240 B region.
  for (int half = 4; half >= 1; half >>= 1) {
    __syncthreads();
    if (w >= half && w < 2 * half) {
      float* dst = Red + (w - half) * 2560;
#pragma unroll
      for (int it = 0; it < 2; ++it) {
#pragma unroll
        for (int ct = 0; ct < 4; ++ct)
          *(f32x4*)&dst[(it * 4 + ct) * 256 + lane * 4] = oacc[it][ct];
        *(f32x4*)&dst[(8 + it) * 256 + lane * 4] = lacc[it];
      }
    }
    __syncthreads();
    if (w < half) {
      const float* src = Red + w * 2560;
#pragma unroll
      for (int it = 0; it < 2; ++it) {
#pragma unroll
        for (int ct = 0; ct < 4; ++ct)
          oacc[it][ct] = oacc[it][ct] + *(const f32x4*)&src[(it * 4 + ct) * 256 + lane * 4];
        lacc[it] = lacc[it] + *(const f32x4*)&src[(8 + it) * 256 + lane * 4];
      }
    }
  }

  // ---- wave 0: normalize + transpose into tr[c][i] (region 1, dead space)
  float* tr = Red + 2560;
  if (w == 0) {
    const float gm = gamma_p[0];
#pragma unroll
    for (int it = 0; it < 2; ++it) {
      f32x4 sc;
#pragma unroll
      for (int r = 0; r < 4; ++r) sc[r] = gm / lacc[it][r];
#pragma unroll
      for (int ct = 0; ct < 4; ++ct)
#pragma unroll
        for (int r = 0; r < 4; ++r)
          tr[(ct * 16 + c15) * 33 + it * 16 + g * 4 + r] = oacc[it][ct][r] * sc[r];
    }
  }
  __syncthreads();

  // ---- cooperative epilogue: out = tr + BN_PReLU(y), 512 thr x 4 floats
  const float a = pa[0];
  {
    int c = tid >> 3, i4 = (tid & 7) * 4;
    const float A = ABg[c], Bc = ABg[64 + c];
    const size_t idx = (size_t)(b * 64 + c) * 4096 + i32 * 32 + i4;
    float4 yv = *(const float4*)&y[idx];
    float t;
    float4 ov;
    t = fmaf(A, yv.x, Bc); t = t >= 0.f ? t : a * t; ov.x = tr[c * 33 + i4 + 0] + t;
    t = fmaf(A, yv.y, Bc); t = t >= 0.f ? t : a * t; ov.y = tr[c * 33 + i4 + 1] + t;
    t = fmaf(A, yv.z, Bc); t = t >= 0.f ? t : a * t; ov.z = tr[c * 33 + i4 + 2] + t;
    t = fmaf(A, yv.w, Bc); t = t >= 0.f ? t : a * t; ov.w = tr[c * 33 + i4 + 3] + t;
    *(float4*)&out[idx] = ov;
  }
}

extern "C" void kernel_launch(void* const* d_in, const int* in_sizes, int n_in,
                              void* d_out, int out_size, void* d_ws, size_t ws_size,
                              hipStream_t stream) {
  (void)in_sizes; (void)n_in; (void)out_size; (void)ws_size;
  const float* x        = (const float*)d_in[0];
  const float* conv_w   = (const float*)d_in[1];
  const float* conv_b   = (const float*)d_in[2];
  const float* bn_scale = (const float*)d_in[3];
  const float* bn_bias  = (const float*)d_in[4];
  const float* prelu_a  = (const float*)d_in[5];
  const float* gamma    = (const float*)d_in[6];
  float* out = (float*)d_out;

  u16* fbfA = (u16*)d_ws;                              // 1,048,576 u16 (2 MB)
  u16* fbfB = fbfA + kB * kC * kN;                     // 1,048,576 u16 (2 MB)
  float* stat = (float*)(fbfB + kB * kC * kN);         // 512 f32 (4 shards x 128)
  float* ABg = stat + 512;                             // 128 f32
  u16* wA = (u16*)(ABg + 128);                         // 36,864 u16

  float* y = out;  // conv scratch in d_out; overwritten element-wise by attn tail

  prep_w_kernel<<<144, 256, 0, stream>>>(conv_w, wA, stat);
  conv_kernel<<<kB * kH * 2, 256, 0, stream>>>(x, wA, conv_b, y, stat);
  pack_kernel<<<kB * (kN / 64), 256, 0, stream>>>(y, stat, bn_scale, bn_bias, prelu_a,
                                                  ABg, fbfA, fbfB);
  attn_kernel<<<kB * 128, 512, 0, stream>>>(fbfA, fbfB, y, ABg, prelu_a, gamma, out);
}

// Round 10
// 115.780 us; speedup vs baseline: 1.0391x; 1.0391x over previous
//
#include <hip/hip_runtime.h>

constexpr int kB = 4, kC = 64, kH = 64, kW = 64, kN = kH * kW;
constexpr float kEps = 1e-5f;
// sqrt(log2(e)): folded into fbfA (used for BOTH Q and K) so S = QK^T lands in
// the log2 domain and exp becomes a bare v_exp_f32.
constexpr float kQS = 1.2011224087864498f;

#if __has_builtin(__builtin_amdgcn_exp2f)
#define EXP2F(x) __builtin_amdgcn_exp2f(x)
#else
#define EXP2F(x) exp2f(x)
#endif

typedef __attribute__((ext_vector_type(8))) short short8;
typedef __attribute__((ext_vector_type(4))) float f32x4;
typedef unsigned short u16;

__device__ inline unsigned pkbf(float a, float b) {  // RNE pack (pack path only)
  unsigned ua = __float_as_uint(a), ub = __float_as_uint(b);
  ua += 0x7fff + ((ua >> 16) & 1);
  ub += 0x7fff + ((ub >> 16) & 1);
  return (ua >> 16) | (ub & 0xffff0000u);
}

// ---- w[oc][ic][3][3] fp32 -> wA bf16 [oc][khw*64 + ic]; also zero stat shards
__global__ __launch_bounds__(256) void prep_w_kernel(const float* __restrict__ w,
                                                     u16* __restrict__ wA,
                                                     float* __restrict__ stat) {
  if (blockIdx.x == 0) {  // 4 shards x (64 sum + 64 sumsq)
    stat[threadIdx.x] = 0.f;
    stat[256 + threadIdx.x] = 0.f;
  }
  int idx = blockIdx.x * 256 + threadIdx.x;
  if (idx < 64 * 576) {
    int oc = idx / 576, r = idx - oc * 576;
    int khw = r >> 6, ic = r & 63;
    float v = w[(oc * 64 + ic) * 9 + khw];
    unsigned u = __float_as_uint(v);
    u += 0x7fff + ((u >> 16) & 1);
    wA[idx] = (u16)(u >> 16);
  }
}

// ---- conv 3x3 SAME + bias, bf16 MFMA implicit GEMM. block=(b,h,whalf), 4 waves.
//      Fused: per-channel sum/sumsq via in-wave shuffle reduce + sharded atomics.
__global__ __launch_bounds__(256) void conv_kernel(const float* __restrict__ x,
                                                   const u16* __restrict__ wA,
                                                   const float* __restrict__ bias,
                                                   float* __restrict__ y,
                                                   float* __restrict__ stat) {
  const int tid = threadIdx.x;
  const int lane = tid & 63;
  const int wv = tid >> 6;
  const int bx = blockIdx.x;
  const int b = bx >> 7;
  const int h = (bx & 127) >> 1;
  const int w0 = (bx & 1) * 32;
  const int lw = lane & 15, lg = lane >> 4;

  // xt[kh][wc 0..39][ic], wc <-> w = w0-4+wc ; ic-chunk8 swizzled by wc&7
  __shared__ __align__(16) u16 xt[3 * 40 * 64];

#pragma unroll
  for (int rep = 0; rep < 4; ++rep) {
    int idx = rep * 256 + tid;
    if (idx < 960) {
      int kh = idx / 320;
      int t = idx - kh * 320;
      int gw = t >> 5, icp = t & 31;
      int wb = w0 - 4 + gw * 4;
      int hh = h + kh - 1;
      float4 va = {0.f, 0.f, 0.f, 0.f}, vb = {0.f, 0.f, 0.f, 0.f};
      if (hh >= 0 && hh < 64 && wb >= 0 && wb < 64) {
        va = *(const float4*)&x[((b * 64 + icp * 2) * 64 + hh) * 64 + wb];
        vb = *(const float4*)&x[((b * 64 + icp * 2 + 1) * 64 + hh) * 64 + wb];
      }
      float av[4] = {va.x, va.y, va.z, va.w};
      float bv[4] = {vb.x, vb.y, vb.z, vb.w};
#pragma unroll
      for (int j = 0; j < 4; ++j) {
        int wc = gw * 4 + j;
        *(unsigned*)&xt[(kh * 40 + wc) * 64 + (((icp >> 2) ^ (wc & 7)) * 8 + (icp & 3) * 2)] =
            pkbf(av[j], bv[j]);
      }
    }
  }
  __syncthreads();

  const int oc0 = wv * 16;
  short8 af[18];
#pragma unroll
  for (int kc = 0; kc < 18; ++kc)
    af[kc] = *(const short8*)&wA[(oc0 + lw) * 576 + kc * 32 + lg * 8];

  f32x4 acc[2];
  acc[0] = (f32x4){0.f, 0.f, 0.f, 0.f};
  acc[1] = (f32x4){0.f, 0.f, 0.f, 0.f};
#pragma unroll
  for (int kc = 0; kc < 18; ++kc) {
    const int khw = kc >> 1;
    const int kh = khw / 3, kwv = khw % 3;
#pragma unroll
    for (int nt = 0; nt < 2; ++nt) {
      int wc = nt * 16 + lw + kwv + 3;
      short8 bf = *(const short8*)&xt[(kh * 40 + wc) * 64 + ((((kc & 1) * 4 + lg) ^ (wc & 7)) * 8)];
      acc[nt] = __builtin_amdgcn_mfma_f32_16x16x32_bf16(af[kc], bf, acc[nt], 0, 0, 0);
    }
  }

  float* st = stat + (bx & 3) * 128;  // 4 shards cut per-address atomic depth
#pragma unroll
  for (int r = 0; r < 4; ++r) {
    const int oc = oc0 + lg * 4 + r;
    const float bz = bias[oc];
    float v0 = acc[0][r] + bz;
    float v1 = acc[1][r] + bz;
    y[((b * 64 + oc) * 64 + h) * 64 + w0 + lw] = v0;
    y[((b * 64 + oc) * 64 + h) * 64 + w0 + 16 + lw] = v1;
    float s = v0 + v1, q = v0 * v0 + v1 * v1;
#pragma unroll
    for (int m = 1; m < 16; m <<= 1) {
      s += __shfl_xor(s, m);
      q += __shfl_xor(q, m);
    }
    if (lw == 0) {
      atomicAdd(&st[oc], s);
      atomicAdd(&st[64 + oc], q);
    }
  }
}

// ---- BN + PReLU -> fbfA (frag layout: pos=lane&15, ch=k, scaled by kQS);
//      fbfB (frag layout: ch=lane&15, pos=k). Computes A/B from fused stats,
//      publishes ABg for the attn epilogue.
__global__ __launch_bounds__(256) void pack_kernel(const float* __restrict__ y,
                                                   const float* __restrict__ stat,
                                                   const float* __restrict__ scale,
                                                   const float* __restrict__ bias,
                                                   const float* __restrict__ pa,
                                                   float* __restrict__ ABg,
                                                   u16* __restrict__ fbfA,
                                                   u16* __restrict__ fbfB) {
  __shared__ float ls[64 * 65];
  __shared__ float sAB[128];
  const int tid = threadIdx.x;
  const int b = blockIdx.x >> 6;
  const int n0 = (blockIdx.x & 63) << 6;
  if (tid < 64) {
    const float inv_n = 1.f / (float)(kB * kN);
    float ssum = stat[tid] + stat[128 + tid] + stat[256 + tid] + stat[384 + tid];
    float qsum = stat[64 + tid] + stat[192 + tid] + stat[320 + tid] + stat[448 + tid];
    float mean = ssum * inv_n;
    float var = qsum * inv_n - mean * mean;
    float A = scale[tid] * rsqrtf(var + kEps);
    float Bc = bias[tid] - mean * A;
    sAB[tid] = A;
    sAB[64 + tid] = Bc;
    ABg[tid] = A;       // redundant identical writes across blocks: benign
    ABg[64 + tid] = Bc;
  }
  __syncthreads();
  {
    const int c = tid >> 2, nj = (tid & 3) << 4;
    const float A = sAB[c], Bc = sAB[64 + c], a = pa[0];
    const float* yp = y + ((b * kC + c) * kN) + n0 + nj;
    float f[16];
#pragma unroll
    for (int v = 0; v < 4; ++v) {
      float4 xv = *(const float4*)(yp + v * 4);
      float t;
      t = fmaf(A, xv.x, Bc); f[v * 4 + 0] = t >= 0.f ? t : a * t;
      t = fmaf(A, xv.y, Bc); f[v * 4 + 1] = t >= 0.f ? t : a * t;
      t = fmaf(A, xv.z, Bc); f[v * 4 + 2] = t >= 0.f ? t : a * t;
      t = fmaf(A, xv.w, Bc); f[v * 4 + 3] = t >= 0.f ? t : a * t;
    }
#pragma unroll
    for (int v = 0; v < 16; ++v) ls[c * 65 + nj + v] = f[v];
  }
  __syncthreads();
  {  // fbfA: chunk = (pt within block 0..3, kc 0..1); 64 lanes x 16B per chunk
    int chunk = tid >> 5, pt = chunk >> 1, kc = chunk & 1;
    int lp2 = (tid & 31) * 2;
    u16* dst = fbfA + ((size_t)((b * 256 + (n0 >> 4) + pt) * 2 + kc)) * 512;
#pragma unroll
    for (int e = 0; e < 2; ++e) {
      int L = lp2 + e;
      int n = pt * 16 + (L & 15);
      int cb = kc * 32 + (L >> 4) * 8;
      float v[8];
#pragma unroll
      for (int r = 0; r < 8; ++r) v[r] = kQS * ls[(cb + r) * 65 + n];
      uint4 o = {pkbf(v[0], v[1]), pkbf(v[2], v[3]), pkbf(v[4], v[5]), pkbf(v[6], v[7])};
      *(uint4*)&dst[L * 8] = o;
    }
  }
  {  // fbfB: chunk = (jt 0..1, ct 0..3)
    int chunk = tid >> 5, jt = chunk >> 2, ct = chunk & 3;
    int lp2 = (tid & 31) * 2;
    u16* dst = fbfB + ((size_t)((b * 128 + (n0 >> 5) + jt) * 4 + ct)) * 512;
#pragma unroll
    for (int e = 0; e < 2; ++e) {
      int L = lp2 + e;
      int c = ct * 16 + (L & 15);
      int nb = jt * 32 + (L >> 4) * 8;
      float v[8];
#pragma unroll
      for (int r = 0; r < 8; ++r) v[r] = ls[c * 65 + nb + r];
      uint4 o = {pkbf(v[0], v[1]), pkbf(v[2], v[3]), pkbf(v[4], v[5]), pkbf(v[6], v[7])};
      *(uint4*)&dst[L * 8] = o;
    }
  }
}

// ---- FULL-j flash attention with fused epilogue (R8 geometry, proven 115.8).
//      block=(b,it4): 256 blocks x 8 waves. Every wave computes the SAME 4
//      Q-tiles (64 i-rows) over an interleaved 1/8 slice of all 128 j-tiles
//      (16 jj iters, full 36-MFMA-per-8KB intensity). 3-stage LDS tree
//      reduction -> block-local normalization: no partials, no combine.
//      NEW vs R8: s_setprio(1) around MFMA clusters (waves drift out of phase
//      in the barrier-free loop -> scheduler favors MFMA-entering waves; the
//      regime where learn_hip measured +4-7% on attn).
//      y/out intentionally not __restrict__ (they alias; same-thread RMW).
__global__ __launch_bounds__(512, 1) void attn_kernel(const u16* __restrict__ fbfA,
                                                      const u16* __restrict__ fbfB,
                                                      const float* y,
                                                      const float* __restrict__ ABg,
                                                      const float* __restrict__ pa,
                                                      const float* __restrict__ gamma_p,
                                                      float* out) {
  const int tid = threadIdx.x;
  const int lane = tid & 63;
  const int w = tid >> 6;
  const int bx = blockIdx.x;
  const int b = bx >> 6, it4 = bx & 63;
  const int c15 = lane & 15, g = lane >> 4;

  // 80 KB union: [0,40960) per-wave P staging during the loop;
  // 4 x 20480B regions for tree reduction; region 1 reused as tr (16640 B).
  __shared__ __align__(16) float Red[20480];
  u16* ps = (u16*)Red + w * 2560;
  const int pw_off = c15 * 40 + g * 4;   // write base (elements)
  const int pr_off = c15 * 40 + g * 8;   // b128 read base

  const uint4* fA = (const uint4*)fbfA;
  const uint4* fB = (const uint4*)fbfB;

  // Q frags (negated; fbfA pre-scaled by sqrt(log2e) so S is log2-domain)
  uint4 qf[4][2];
#pragma unroll
  for (int it = 0; it < 4; ++it)
#pragma unroll
    for (int kc = 0; kc < 2; ++kc) {
      uint4 q = fA[(size_t)((b * 256 + it4 * 4 + it) * 2 + kc) * 64 + lane];
      q.x ^= 0x80008000u; q.y ^= 0x80008000u; q.z ^= 0x80008000u; q.w ^= 0x80008000u;
      qf[it][kc] = q;
    }

  const short8 ones = {0x3F80, 0x3F80, 0x3F80, 0x3F80, 0x3F80, 0x3F80, 0x3F80, 0x3F80};

  f32x4 oacc[4][4];
  f32x4 lacc[4];
#pragma unroll
  for (int it = 0; it < 4; ++it) {
    lacc[it] = (f32x4){0.f, 0.f, 0.f, 0.f};
#pragma unroll
    for (int ct = 0; ct < 4; ++ct) oacc[it][ct] = (f32x4){0.f, 0.f, 0.f, 0.f};
  }

#pragma unroll 2
  for (int jj2 = 0; jj2 < 16; ++jj2) {
    const int jj = jj2 * 8 + w;  // interleaved: 8 waves cover all 128 j-tiles
    // fragment loads (coalesced 1KB each, L1/L2-resident)
    const int ca = (b * 256 + jj * 2) * 2;
    uint4 a00 = fA[(size_t)(ca + 0) * 64 + lane];
    uint4 a01 = fA[(size_t)(ca + 1) * 64 + lane];
    uint4 a10 = fA[(size_t)(ca + 2) * 64 + lane];
    uint4 a11 = fA[(size_t)(ca + 3) * 64 + lane];
    const int cb = (b * 128 + jj) * 4;
    uint4 v0 = fB[(size_t)(cb + 0) * 64 + lane];
    uint4 v1 = fB[(size_t)(cb + 1) * 64 + lane];
    uint4 v2 = fB[(size_t)(cb + 2) * 64 + lane];
    uint4 v3 = fB[(size_t)(cb + 3) * 64 + lane];

    // S^T tiles (log2 domain): D[m=j][n=i]
    f32x4 sv[2][4];
    __builtin_amdgcn_s_setprio(1);
#pragma unroll
    for (int it = 0; it < 4; ++it) {
      f32x4 z0 = (f32x4){0.f, 0.f, 0.f, 0.f};
      z0 = __builtin_amdgcn_mfma_f32_16x16x32_bf16(*(short8*)&a00, *(short8*)&qf[it][0], z0, 0, 0, 0);
      z0 = __builtin_amdgcn_mfma_f32_16x16x32_bf16(*(short8*)&a01, *(short8*)&qf[it][1], z0, 0, 0, 0);
      sv[0][it] = z0;
      f32x4 z1 = (f32x4){0.f, 0.f, 0.f, 0.f};
      z1 = __builtin_amdgcn_mfma_f32_16x16x32_bf16(*(short8*)&a10, *(short8*)&qf[it][0], z1, 0, 0, 0);
      z1 = __builtin_amdgcn_mfma_f32_16x16x32_bf16(*(short8*)&a11, *(short8*)&qf[it][1], z1, 0, 0, 0);
      sv[1][it] = z1;
    }
    __builtin_amdgcn_s_setprio(0);
    // P = exp2(S) packed to per-wave LDS [i][j] (v_perm RTZ bf16 pack)
#pragma unroll
    for (int it = 0; it < 4; ++it)
#pragma unroll
      for (int jt = 0; jt < 2; ++jt) {
        float p0 = EXP2F(sv[jt][it][0]);
        float p1 = EXP2F(sv[jt][it][1]);
        float p2 = EXP2F(sv[jt][it][2]);
        float p3 = EXP2F(sv[jt][it][3]);
        uint2 d;
        d.x = __builtin_amdgcn_perm(__float_as_uint(p1), __float_as_uint(p0), 0x07060302u);
        d.y = __builtin_amdgcn_perm(__float_as_uint(p3), __float_as_uint(p2), 0x07060302u);
        *(uint2*)&ps[pw_off + it * 640 + jt * 16] = d;
      }
    // PV + l (ones-frag row sums)
    __builtin_amdgcn_s_setprio(1);
#pragma unroll
    for (int it = 0; it < 4; ++it) {
      short8 pf = *(const short8*)&ps[pr_off + it * 640];
      lacc[it] = __builtin_amdgcn_mfma_f32_16x16x32_bf16(pf, ones, lacc[it], 0, 0, 0);
      oacc[it][0] = __builtin_amdgcn_mfma_f32_16x16x32_bf16(pf, *(short8*)&v0, oacc[it][0], 0, 0, 0);
      oacc[it][1] = __builtin_amdgcn_mfma_f32_16x16x32_bf16(pf, *(short8*)&v1, oacc[it][1], 0, 0, 0);
      oacc[it][2] = __builtin_amdgcn_mfma_f32_16x16x32_bf16(pf, *(short8*)&v2, oacc[it][2], 0, 0, 0);
      oacc[it][3] = __builtin_amdgcn_mfma_f32_16x16x32_bf16(pf, *(short8*)&v3, oacc[it][3], 0, 0, 0);
    }
    __builtin_amdgcn_s_setprio(0);
  }

  // ---- 3-stage tree reduction: 8 -> 4 -> 2 -> 1 waves (uniform barriers).
  for (int half = 4; half >= 1; half >>= 1) {
    __syncthreads();
    if (w >= half && w < 2 * half) {
      float* dst = Red + (w - half) * 5120;
#pragma unroll
      for (int it = 0; it < 4; ++it) {
#pragma unroll
        for (int ct = 0; ct < 4; ++ct)
          *(f32x4*)&dst[(it * 4 + ct) * 256 + lane * 4] = oacc[it][ct];
        *(f32x4*)&dst[(16 + it) * 256 + lane * 4] = lacc[it];
      }
    }
    __syncthreads();
    if (w < half) {
      const float* src = Red + w * 5120;
#pragma unroll
      for (int it = 0; it < 4; ++it) {
#pragma unroll
        for (int ct = 0; ct < 4; ++ct)
          oacc[it][ct] = oacc[it][ct] + *(const f32x4*)&src[(it * 4 + ct) * 256 + lane * 4];
        lacc[it] = lacc[it] + *(const f32x4*)&src[(16 + it) * 256 + lane * 4];
      }
    }
  }

  // ---- wave 0: normalize + transpose into tr[c][i] (region 1, dead space)
  float* tr = Red + 5120;
  if (w == 0) {
    const float gm = gamma_p[0];
#pragma unroll
    for (int it = 0; it < 4; ++it) {
      f32x4 sc;
#pragma unroll
      for (int r = 0; r < 4; ++r) sc[r] = gm / lacc[it][r];
#pragma unroll
      for (int ct = 0; ct < 4; ++ct)
#pragma unroll
        for (int r = 0; r < 4; ++r)
          tr[(ct * 16 + c15) * 65 + it * 16 + g * 4 + r] = oacc[it][ct][r] * sc[r];
    }
  }
  __syncthreads();

  // ---- cooperative epilogue: out = tr + BN_PReLU(y), 512 thr x 8 floats
  const float a = pa[0];
#pragma unroll
  for (int rr = 0; rr < 2; ++rr) {
    int flat4 = rr * 512 + tid;
    int c = flat4 >> 4, i4 = (flat4 & 15) * 4;
    const float A = ABg[c], Bc = ABg[64 + c];
    const size_t idx = (size_t)(b * 64 + c) * 4096 + it4 * 64 + i4;
    float4 yv = *(const float4*)&y[idx];
    float t;
    float4 ov;
    t = fmaf(A, yv.x, Bc); t = t >= 0.f ? t : a * t; ov.x = tr[c * 65 + i4 + 0] + t;
    t = fmaf(A, yv.y, Bc); t = t >= 0.f ? t : a * t; ov.y = tr[c * 65 + i4 + 1] + t;
    t = fmaf(A, yv.z, Bc); t = t >= 0.f ? t : a * t; ov.z = tr[c * 65 + i4 + 2] + t;
    t = fmaf(A, yv.w, Bc); t = t >= 0.f ? t : a * t; ov.w = tr[c * 65 + i4 + 3] + t;
    *(float4*)&out[idx] = ov;
  }
}

extern "C" void kernel_launch(void* const* d_in, const int* in_sizes, int n_in,
                              void* d_out, int out_size, void* d_ws, size_t ws_size,
                              hipStream_t stream) {
  (void)in_sizes; (void)n_in; (void)out_size; (void)ws_size;
  const float* x        = (const float*)d_in[0];
  const float* conv_w   = (const float*)d_in[1];
  const float* conv_b   = (const float*)d_in[2];
  const float* bn_scale = (const float*)d_in[3];
  const float* bn_bias  = (const float*)d_in[4];
  const float* prelu_a  = (const float*)d_in[5];
  const float* gamma    = (const float*)d_in[6];
  float* out = (float*)d_out;

  u16* fbfA = (u16*)d_ws;                              // 1,048,576 u16 (2 MB)
  u16* fbfB = fbfA + kB * kC * kN;                     // 1,048,576 u16 (2 MB)
  float* stat = (float*)(fbfB + kB * kC * kN);         // 512 f32 (4 shards x 128)
  float* ABg = stat + 512;                             // 128 f32
  u16* wA = (u16*)(ABg + 128);                         // 36,864 u16

  float* y = out;  // conv scratch in d_out; overwritten element-wise by attn tail

  prep_w_kernel<<<144, 256, 0, stream>>>(conv_w, wA, stat);
  conv_kernel<<<kB * kH * 2, 256, 0, stream>>>(x, wA, conv_b, y, stat);
  pack_kernel<<<kB * (kN / 64), 256, 0, stream>>>(y, stat, bn_scale, bn_bias, prelu_a,
                                                  ABg, fbfA, fbfB);
  attn_kernel<<<kB * 64, 512, 0, stream>>>(fbfA, fbfB, y, ABg, prelu_a, gamma, out);
}